// Round 8
// baseline (194.701 us; speedup 1.0000x reference)
//
#include <hip/hip_runtime.h>

// GRU decoder via MFMA, round 8: B=32768, T=48, F=16, H=32.
// PAIR-SPLIT blocks (2 waves x 16 batch rows; wave w owns hidden half).
// Changes vs round 7 (77 us, VALU-volume-limited):
//  - po folded into the MFMA via dead K-slot 16: weight rows k>=16 were all
//    zero; row k=16 now carries the prev-out weights (Wk row 0) and quad-2
//    lanes insert bf16(po) into their j=0 B-slot (one cndmask). Removes the
//    3x4 rank-1 fmas from the head of the gate/trans chain.
//  - xa zero-mask DELETED: K-slots 16..31 multiply zero *weights*, so
//    garbage B-frag values there contribute exactly 0 (feat loads are finite).
//  - feat prefetch deepened to 2 steps (load t+2 during step t): HBM latency
//    can never reach the chain even when a step runs < ~900 cyc.
// Kept from r7: raw s_barrier with lgkm-only waitcnt (0xC07F), double-buffered
// h exchange + posum, log2e pre-scaled weights (activation = rcp(1+exp2(x))
// via __builtin_amdgcn_exp2f), LDS obuf with coalesced final flush.
// Layouts (verified m89/m91/m120):
//   D[m=gatecol][n=batchcol]: col=lane&15=batch, row=(lane>>4)*4+reg=gatecol
//   A[m=lane&15][k=(lane>>4)*8+j] ; B[k=(lane>>4)*8+j][n=lane&15]

typedef __attribute__((ext_vector_type(8))) short short8;
typedef __attribute__((ext_vector_type(4))) float f32x4;

constexpr int T_STEPS  = 48;
constexpr int F_DIM    = 16;
constexpr int H_DIM    = 32;
constexpr int ROW_SH   = 40;              // shorts per h-row (80 B, 16B-aligned)
constexpr int HX_SH    = 16 * ROW_SH;     // one h buffer: 640 shorts
constexpr int O_STRIDE = 17;              // obuf leading stride (floats)

union S8 { short8 s; unsigned u[4]; };

__device__ __forceinline__ unsigned pk_bf16(float hi, float lo) {
    // (bf16(hi)<<16)|bf16(lo), round-half-up
    return __builtin_amdgcn_perm(__float_as_uint(hi) + 0x8000u,
                                 __float_as_uint(lo) + 0x8000u, 0x07060302u);
}
__device__ __forceinline__ short bf16s(float x) {
    return (short)((__float_as_uint(x) + 0x8000u) >> 16);
}
__device__ __forceinline__ float rcpf(float x) { return __builtin_amdgcn_rcpf(x); }
__device__ __forceinline__ float ex2(float x)  { return __builtin_amdgcn_exp2f(x); }
#define MFMA(a, b, c) __builtin_amdgcn_mfma_f32_16x16x32_bf16(a, b, c, 0, 0, 0)
#define SWZ16(v) __int_as_float(__builtin_amdgcn_ds_swizzle(__float_as_int(v), 0x401F))
#define BPERM(a, v) __builtin_amdgcn_ds_bpermute((a), (v))

__global__ __launch_bounds__(128, 4)
void gru_mfma8(const float* __restrict__ feat,     // [B,T,F]
               const float* __restrict__ init_in,  // [B,1]
               const float* __restrict__ init_h,   // [B,H]
               const float* __restrict__ Wk,       // [17,96]
               const float* __restrict__ Rk,       // [32,96]
               const float* __restrict__ bx,       // [96]
               const float* __restrict__ bh,       // [96]
               const float* __restrict__ dw,       // [32]
               const float* __restrict__ db,       // [1]
               float* __restrict__ out)            // [B,T]
{
    __shared__ __align__(16) short hx[2 * HX_SH];          // double-buffered h tile
    __shared__ float posum[2][2][16];                      // [parity][wave][col]
    __shared__ __align__(16) float obuf[T_STEPS * O_STRIDE];

    const int lane = threadIdx.x & 63;
    const int w    = threadIdx.x >> 6;        // 0/1: hidden half owned
    const int ln   = lane & 15;               // batch col
    const int quad = lane >> 4;
    const int b0   = blockIdx.x * 16;
    const int bpa  = (lane ^ 32) << 2;        // xor32 bpermute addr
    const bool isq2 = (quad == 2);            // po K-slot owner (k=16, j=0)

    const float SZ = -1.44269504088896340736f;   // -log2(e)  (sigmoid args)
    const float SC =  2.88539008177792681472f;   // 2*log2(e) (tanh arg)

    // ---- weight fragments for this wave's hidden half (A-operand) ----
    // k<16: feature rows (kernel rows 1..16); k==16: prev_out row (kernel
    // row 0) -- pairs with bf16(po) in the B-frag; k>16: zero.
    S8 Wfz, Wfr, Wfh, Rfz, Rfr, Rfh;
#pragma unroll
    for (int j = 0; j < 8; ++j) {
        const int k = quad * 8 + j;
        const int n = w * 16 + ln;
        float wz = 0.0f, wr = 0.0f, wh = 0.0f;
        if (k < 16) {
            wz = SZ * Wk[(size_t)(k + 1) * 96 + n];
            wr = SZ * Wk[(size_t)(k + 1) * 96 + 32 + n];
            wh = SC * Wk[(size_t)(k + 1) * 96 + 64 + n];
        } else if (k == 16) {
            wz = SZ * Wk[n];
            wr = SZ * Wk[32 + n];
            wh = SC * Wk[64 + n];
        }
        Wfz.s[j] = bf16s(wz); Wfr.s[j] = bf16s(wr); Wfh.s[j] = bf16s(wh);
        Rfz.s[j] = bf16s(SZ * Rk[(size_t)k * 96 + n]);
        Rfr.s[j] = bf16s(SZ * Rk[(size_t)k * 96 + 32 + n]);
        Rfh.s[j] = bf16s(SC * Rk[(size_t)k * 96 + 64 + n]);
    }

    // ---- per-lane constants for this wave's 4 gate elements ----
    float bz4[4], br4[4], bxh4[4], bhh4[4], dw4[4];
#pragma unroll
    for (int i = 0; i < 4; ++i) {
        const int c = w * 16 + quad * 4 + i;       // hidden unit index in [0,32)
        bz4[i]  = SZ * (bx[c] + bh[c]);
        br4[i]  = SZ * (bx[32 + c] + bh[32 + c]);
        bxh4[i] = SC * bx[64 + c];
        bhh4[i] = SC * bh[64 + c];
        dw4[i]  = dw[c];
    }
    const float dbs = db[0];

    // ---- initial state ----
    float hc[4];
#pragma unroll
    for (int i = 0; i < 4; ++i)
        hc[i] = init_h[(size_t)(b0 + ln) * H_DIM + w * 16 + quad * 4 + i];
    S8 hB;                                         // full-H B-frag (both halves)
    {
        const float* hp = init_h + (size_t)(b0 + ln) * H_DIM + quad * 8;
        const f32x4 a = *(const f32x4*)hp;
        const f32x4 b = *(const f32x4*)(hp + 4);
        hB.u[0] = pk_bf16(a[1], a[0]); hB.u[1] = pk_bf16(a[3], a[2]);
        hB.u[2] = pk_bf16(b[1], b[0]); hB.u[3] = pk_bf16(b[3], b[2]);
    }
    float po = init_in[b0 + ln];

    // ---- 2-deep feat prefetch (t=0 and t=1 in flight before the loop) ----
    const float* fqb = feat + (size_t)(b0 + ln) * (T_STEPS * F_DIM) + (quad & 1) * 8;
    f32x4 P[2][2];
    P[0][0] = *(const f32x4*)(fqb);
    P[0][1] = *(const f32x4*)(fqb + 4);
    P[1][0] = *(const f32x4*)(fqb + F_DIM);
    P[1][1] = *(const f32x4*)(fqb + F_DIM + 4);

    // LDS addresses for the h exchange
    unsigned* hwr = (unsigned*)(hx + ln * ROW_SH + w * 16 + quad * 4);  // write own half
    const short8* hrd = (const short8*)(hx + ln * ROW_SH + quad * 8);   // read full

    for (int t = 0; t < T_STEPS; ++t) {
        const int p = t & 1;                       // LDS buffer parity

        // x B-frag from prefetched regs; quad2 j=0 slot carries bf16(po);
        // K-slots >16 are garbage * zero-weight = 0 (no mask needed)
        const f32x4 ca = P[p][0];
        const f32x4 cb = P[p][1];
        S8 xa;
        const unsigned u0 = pk_bf16(ca[1], ca[0]);
        xa.u[0] = isq2 ? (unsigned)(unsigned short)bf16s(po) : u0;
        xa.u[1] = pk_bf16(ca[3], ca[2]);
        xa.u[2] = pk_bf16(cb[1], cb[0]);
        xa.u[3] = pk_bf16(cb[3], cb[2]);

        // prefetch feat(t+2) into the slot just consumed
        const int t2 = (t < T_STEPS - 2) ? t + 2 : T_STEPS - 1;
        P[p][0] = *(const f32x4*)(fqb + t2 * F_DIM);
        P[p][1] = *(const f32x4*)(fqb + t2 * F_DIM + 4);

        // 6 MFMAs for this wave's hidden half (po term rides the x-side)
        f32x4 aZ  = {bz4[0],  bz4[1],  bz4[2],  bz4[3]};
        f32x4 aR  = {br4[0],  br4[1],  br4[2],  br4[3]};
        f32x4 aXH = {bxh4[0], bxh4[1], bxh4[2], bxh4[3]};
        f32x4 aHH = {bhh4[0], bhh4[1], bhh4[2], bhh4[3]};
        aZ  = MFMA(Wfz.s, xa.s, aZ);
        aR  = MFMA(Wfr.s, xa.s, aR);
        aXH = MFMA(Wfh.s, xa.s, aXH);
        aZ  = MFMA(Rfz.s, hB.s, aZ);
        aR  = MFMA(Rfr.s, hB.s, aR);
        aHH = MFMA(Rfh.s, hB.s, aHH);

        // gates (pre-scaled: activation = rcp(1+exp2(x))), po already inside
        float hn[4];
#pragma unroll
        for (int i = 0; i < 4; ++i) {
            const float zz = rcpf(1.0f + ex2(aZ[i]));
            const float rr = rcpf(1.0f + ex2(aR[i]));
            const float vv = fmaf(rr, aHH[i], aXH[i]);
            const float cc = fmaf(-2.0f, rcpf(1.0f + ex2(vv)), 1.0f);  // tanh
            const float h2 = cc + zz * (hc[i] - cc);
            hc[i] = h2;
            hn[i] = h2;
        }

        // dense half-sum over this wave's 16 hidden units
        const float d01 = fmaf(hn[0], dw4[0], hn[1] * dw4[1]);
        const float d23 = fmaf(hn[2], dw4[2], hn[3] * dw4[3]);
        float s = d01 + d23;
        s += SWZ16(s);
        s += __int_as_float(BPERM(bpa, __float_as_int(s)));   // sum over quads

        // publish own half: h_new (2x packed u32) + half-sum
        unsigned* hw = hwr + p * (HX_SH / 2);      // HX_SH shorts = HX_SH/2 uints
        hw[0] = pk_bf16(hn[1], hn[0]);
        hw[1] = pk_bf16(hn[3], hn[2]);
        if (lane < 16) posum[p][w][lane] = s;

        // ONE raw barrier: wait DS writes (lgkm only), NOT the vmem prefetch
        __builtin_amdgcn_s_waitcnt(0xC07F);        // lgkmcnt(0), vmcnt/exp free
        __builtin_amdgcn_s_barrier();

        // read full h B-frag + other half-sum
        hB.s = hrd[p * (HX_SH / 8)];               // short8 units: HX_SH/8 per buf
        const float os = posum[p][1 - w][ln];
        po = s + os + dbs;
        if (w == 0 && lane < 16) obuf[t * O_STRIDE + lane] = po;
    }

    // ---- flush outputs (wave 0): coalesced dwordx4 ----
    if (w == 0) {
        const int row = lane >> 2;                 // 0..15
        const int tb  = (lane & 3) * 12;           // 0,12,24,36
        float* orow = out + (size_t)(b0 + row) * T_STEPS + tb;
#pragma unroll
        for (int k = 0; k < 3; ++k) {
            f32x4 v;
#pragma unroll
            for (int e = 0; e < 4; ++e) v[e] = obuf[(tb + k * 4 + e) * O_STRIDE + row];
            *(f32x4*)(orow + k * 4) = v;
        }
    }
}

extern "C" void kernel_launch(void* const* d_in, const int* in_sizes, int n_in,
                              void* d_out, int out_size, void* d_ws, size_t ws_size,
                              hipStream_t stream) {
    const float* feat    = (const float*)d_in[0];
    const float* init_in = (const float*)d_in[1];
    const float* init_h  = (const float*)d_in[2];
    const float* Wk      = (const float*)d_in[3];
    const float* Rk      = (const float*)d_in[4];
    const float* bx      = (const float*)d_in[5];
    const float* bh      = (const float*)d_in[6];
    const float* dw      = (const float*)d_in[7];
    const float* db      = (const float*)d_in[8];
    float* out           = (float*)d_out;

    const int B = in_sizes[2] / H_DIM;      // 32768
    dim3 grid((unsigned)(B / 16));          // one 2-wave block per 16 batch rows
    dim3 block(128);
    hipLaunchKernelGGL(gru_mfma8, grid, block, 0, stream,
                       feat, init_in, init_h, Wk, Rk, bx, bh, dw, db, out);
}